// Round 6
// baseline (3374.609 us; speedup 1.0000x reference)
//
#include <hip/hip_runtime.h>

// ---------------------------------------------------------------------------
// MORAL 2-layer GCN on MI355X — round 6.
//   CSR build rewritten as single-scan two-phase bucket sort:
//     Phase A (bucket_kernel): each XCD scans its 1/8 of edges ONCE (nt),
//       counts deg, packs (dloc<<srcbits|src) into bucket[writerXCD][dstSlice]
//       (append-contiguous per bucket -> no write amplification).
//     Phase B (csrfill_kernel): XCD x drains buckets (*,x) sequentially and
//       cursor-fills its local adj slice (adj+cursor slice L2-resident, no
//       competing stream). Overflow list fallback keeps any distribution
//       correct. Replaces deg_kernel + 8x-rescan fill_kernel (~148 us -> ~45).
// ---------------------------------------------------------------------------

typedef short bf16x8 __attribute__((ext_vector_type(8)));
typedef float f32x4 __attribute__((ext_vector_type(4)));
typedef unsigned short ushort_t;

__device__ __forceinline__ unsigned encf(float f) {
  unsigned u = __float_as_uint(f);
  return (u & 0x80000000u) ? ~u : (u | 0x80000000u);
}
__device__ __forceinline__ float decf(unsigned e) {
  unsigned u = (e & 0x80000000u) ? (e ^ 0x80000000u) : ~e;
  return __uint_as_float(u);
}
__device__ __forceinline__ ushort_t f2bf(float f) {
  unsigned u = __float_as_uint(f);
  u += 0x7FFF + ((u >> 16) & 1);  // RNE
  return (ushort_t)(u >> 16);
}
__device__ __forceinline__ float bf2f(ushort_t h) {
  return __uint_as_float((unsigned)h << 16);
}

// edges may arrive as int32 or int64 (JAX x64 flag unknown). Detect on device.
__global__ void detect_kernel(const int* __restrict__ edges, int E, int* flag64) {
  if (threadIdx.x == 0 && blockIdx.x == 0) {
    int n = (2 * E < 256) ? 2 * E : 256;
    int all_odd_zero = 1;
    for (int i = 1; i < n; i += 2)
      if (edges[i] != 0) { all_odd_zero = 0; break; }
    *flag64 = all_odd_zero;
  }
}

__global__ void init_kernel(unsigned* minenc, unsigned* maxenc, int* deg,
                            int* ctrl, int N) {
  int i = blockIdx.x * blockDim.x + threadIdx.x;
  if (i < 128) { minenc[i] = 0xFFFFFFFFu; maxenc[i] = 0u; ctrl[i] = 0; }
  if (i < N) deg[i] = 0;
}

__global__ void colminmax_kernel(const float* __restrict__ x, unsigned* minenc,
                                 unsigned* maxenc, int N) {
  int g = blockIdx.x * blockDim.x + threadIdx.x;
  int col = g & 127;
  int r0 = g >> 7;
  int nstream = (gridDim.x * blockDim.x) >> 7;
  float mn = 3.4e38f, mx = -3.4e38f;
  for (int r = r0; r < N; r += nstream) {
    float v = x[(size_t)r * 128 + col];
    mn = fminf(mn, v); mx = fmaxf(mx, v);
  }
  atomicMin(&minenc[col], encf(mn));
  atomicMax(&maxenc[col], encf(mx));
}

// Wt1[j][k] = bf16(s[k]*W1[k][j]); cvec[j] = sum_k mn[k]*float(Wt1[j][k])
// Wt2[j][k] = bf16(W2[k][j]); czero = 0
__global__ void prep_kernel(const unsigned* __restrict__ minenc,
                            const unsigned* __restrict__ maxenc,
                            const float* __restrict__ W1, const float* __restrict__ W2,
                            ushort_t* __restrict__ Wt1, ushort_t* __restrict__ Wt2,
                            float* __restrict__ cvec, float* __restrict__ czero) {
  __shared__ float mn_s[128], s_s[128];
  int j = threadIdx.x;
  float mn = decf(minenc[j]);
  float mx = decf(maxenc[j]);
  float denom = (mx > mn) ? (mx - mn) : 1.0f;
  mn_s[j] = mn; s_s[j] = 1.0f / denom;
  __syncthreads();
  float c = 0.f;
  for (int k = 0; k < 128; ++k) {
    float wp = s_s[k] * W1[k * 128 + j];
    ushort_t wb = f2bf(wp);
    Wt1[j * 128 + k] = wb;
    c += mn_s[k] * bf2f(wb);  // fold against the ROUNDED weight so it cancels
    Wt2[j * 128 + k] = f2bf(W2[k * 128 + j]);
  }
  cvec[j] = c;
  czero[j] = 0.f;
}

__global__ void dinv_kernel(const int* __restrict__ deg, float* __restrict__ dinv, int N) {
  int i = blockIdx.x * blockDim.x + threadIdx.x;
  if (i < N) dinv[i] = rsqrtf((float)deg[i] + 1.0f);  // +1 = self loop
}

// ---- prefix scan: deg -> rowptr (exclusive) --------------------------------
#define SB 256

__global__ void scan1_kernel(const int* __restrict__ deg, int* __restrict__ rowptr,
                             int* __restrict__ bsum, int N) {
  __shared__ int tmp[SB];
  int i = blockIdx.x * SB + threadIdx.x;
  int v = (i < N) ? deg[i] : 0;
  tmp[threadIdx.x] = v;
  __syncthreads();
  for (int off = 1; off < SB; off <<= 1) {
    int t = (threadIdx.x >= off) ? tmp[threadIdx.x - off] : 0;
    __syncthreads();
    tmp[threadIdx.x] += t;
    __syncthreads();
  }
  if (i < N) rowptr[i] = tmp[threadIdx.x] - v;
  if (threadIdx.x == 0) bsum[blockIdx.x] = tmp[SB - 1];
}

__global__ void scan2_kernel(int* __restrict__ bsum, int nb) {
  __shared__ int tmp[SB];
  int carry = 0;
  for (int base = 0; base < nb; base += SB) {
    int i = base + threadIdx.x;
    int v = (i < nb) ? bsum[i] : 0;
    tmp[threadIdx.x] = v;
    __syncthreads();
    for (int off = 1; off < SB; off <<= 1) {
      int t = (threadIdx.x >= off) ? tmp[threadIdx.x - off] : 0;
      __syncthreads();
      tmp[threadIdx.x] += t;
      __syncthreads();
    }
    if (i < nb) bsum[i] = carry + tmp[threadIdx.x] - v;
    carry += tmp[SB - 1];
    __syncthreads();
  }
}

__global__ void scan3_kernel(int* __restrict__ rowptr, int* __restrict__ cursor,
                             const int* __restrict__ bsum, int N, int E) {
  int i = blockIdx.x * SB + threadIdx.x;
  if (i < N) {
    int v = rowptr[i] + bsum[blockIdx.x];
    rowptr[i] = v;
    cursor[i] = v;
  }
  if (i == 0) rowptr[N] = E;
}

// ---- Phase A: single-scan deg count + bucket scatter -----------------------
// XCD w scans edges [E*w/8, E*(w+1)/8) once; per edge: deg atomic + append
// packed (dloc<<srcbits | src) to bucket[w*8 + dstSlice]. ctrl layout:
// [0..7] phaseA chunk queues, [8..15] phaseB bucket queues, [16] phaseB
// overflow queue, [32..95] bucket cursors, [96] overflow cursor.
__global__ __launch_bounds__(256) void bucket_kernel(
    const void* __restrict__ edges, int E, const int* __restrict__ flag64,
    int* __restrict__ deg, unsigned* __restrict__ bucket, int cap,
    int* __restrict__ ovf, int ovfcap, int* __restrict__ ctrl,
    int N, int srcbits) {
  int xcd;
  asm volatile("s_getreg_b32 %0, hwreg(HW_REG_XCC_ID)" : "=s"(xcd));
  xcd &= 7;
  int* workq = ctrl + xcd;
  int* bcur = ctrl + 32;
  int* ovfcur = ctrl + 96;
  const int elo = (int)(((long long)E * xcd) >> 3);
  const int ehi = (int)(((long long)E * (xcd + 1)) >> 3);
  const int is64 = *flag64;
  const int ITER = 4, CHUNK = 1024;
  __shared__ int chunk_s;

  for (;;) {
    __syncthreads();
    if (threadIdx.x == 0) chunk_s = atomicAdd(workq, 1);
    __syncthreads();
    int base = elo + chunk_s * CHUNK;
    if (base >= ehi) break;
#pragma unroll
    for (int i = 0; i < ITER; ++i) {
      int e = base + i * 256 + threadIdx.x;
      if (e < ehi) {
        int s, d;
        if (is64) {
          s = (int)__builtin_nontemporal_load((const long long*)edges + e);
          d = (int)__builtin_nontemporal_load((const long long*)edges + E + e);
        } else {
          s = __builtin_nontemporal_load((const int*)edges + e);
          d = __builtin_nontemporal_load((const int*)edges + E + e);
        }
        atomicAdd(&deg[d], 1);
        int slice = (int)(((long long)d << 3) / (long long)N);
        int dloc = d - (int)(((long long)N * slice) >> 3);
        int bi = xcd * 8 + slice;
        int pos = atomicAdd(&bcur[bi], 1);
        if (pos < cap) {
          bucket[(size_t)bi * cap + pos] = ((unsigned)dloc << srcbits) | (unsigned)s;
        } else {
          int op = atomicAdd(ovfcur, 1);
          if (op < ovfcap) { ovf[2 * op] = s; ovf[2 * op + 1] = d; }
        }
      }
    }
  }
}

// ---- Phase B: drain buckets (*, myXCD) -> cursor-fill local adj slice ------
__global__ __launch_bounds__(256) void csrfill_kernel(
    const unsigned* __restrict__ bucket, int cap,
    const int* __restrict__ ovf, int ovfcap,
    int* __restrict__ cursor, int* __restrict__ adj,
    int* __restrict__ ctrl, int N, int srcbits) {
  int xcd;
  asm volatile("s_getreg_b32 %0, hwreg(HW_REG_XCC_ID)" : "=s"(xcd));
  xcd &= 7;
  int* workq = ctrl + 8 + xcd;
  int* ovfq = ctrl + 16;
  const int* bcur = ctrl + 32;
  const unsigned srcmask = (1u << srcbits) - 1u;
  const int nbase = (int)(((long long)N * xcd) >> 3);
  const int ITER = 4, CHUNK = 1024;
  const int nch = (cap + CHUNK - 1) / CHUNK;
  const int total = nch * 8;
  __shared__ int chunk_s;

  for (;;) {
    __syncthreads();
    if (threadIdx.x == 0) chunk_s = atomicAdd(workq, 1);
    __syncthreads();
    int c = chunk_s;
    if (c >= total) break;
    int w = c / nch;
    int off = (c - w * nch) * CHUNK;
    int bi = w * 8 + xcd;
    int len = bcur[bi]; if (len > cap) len = cap;
#pragma unroll
    for (int i = 0; i < ITER; ++i) {
      int e = off + i * 256 + threadIdx.x;
      if (e < len) {
        unsigned pk = bucket[(size_t)bi * cap + e];
        int s = (int)(pk & srcmask);
        int d = nbase + (int)(pk >> srcbits);
        int pos = atomicAdd(&cursor[d], 1);
        adj[pos] = s;
      }
    }
  }

  // overflow tail (shared across all blocks; normally empty)
  int ovlen = ctrl[96]; if (ovlen > ovfcap) ovlen = ovfcap;
  for (;;) {
    __syncthreads();
    if (threadIdx.x == 0) chunk_s = atomicAdd(ovfq, 1);
    __syncthreads();
    int base = chunk_s * CHUNK;
    if (base >= ovlen) break;
#pragma unroll
    for (int i = 0; i < ITER; ++i) {
      int e = base + i * 256 + threadIdx.x;
      if (e < ovlen) {
        int s = ovf[2 * e], d = ovf[2 * e + 1];
        int pos = atomicAdd(&cursor[d], 1);
        adj[pos] = s;
      }
    }
  }
}

// ---- MFMA GEMM: g[bf16] = (X @ Wt^T - cvec) * dinv[row] --------------------
template <int XBF16>
__global__ __launch_bounds__(256) void gemm_mfma_kernel(
    const void* __restrict__ Xv, const ushort_t* __restrict__ Wtg,
    const float* __restrict__ cvec, const float* __restrict__ dinv,
    ushort_t* __restrict__ g, int N) {
  __shared__ ushort_t wt[128 * 128];  // XOR-swizzled: byte = j*256 + (k*2 ^ ((j&7)<<4))
  int t = threadIdx.x;
  for (int c = t; c < 2048; c += 256) {  // 2048 x 16B chunks
    int j = c >> 4;
    int ko = (c & 15) << 4;  // byte offset within row
    uint4 v = *(const uint4*)(Wtg + j * 128 + (ko >> 1));
    *(uint4*)((char*)wt + j * 256 + (ko ^ ((j & 7) << 4))) = v;
  }
  __syncthreads();

  int lane = t & 63, w = t >> 6;
  int lrow = lane & 15;      // A-row / B-col within fragment
  int lk = lane >> 4;        // k-group (8 bf16 each)
  int rowA = blockIdx.x * 64 + w * 16 + lrow;
  int rA = (rowA < N) ? rowA : (N - 1);

  f32x4 acc[8];
#pragma unroll
  for (int i = 0; i < 8; ++i) acc[i] = (f32x4){0.f, 0.f, 0.f, 0.f};

#pragma unroll
  for (int ks = 0; ks < 4; ++ks) {
    int k0 = ks * 32;
    bf16x8 a;
    if (XBF16) {
      a = *(const bf16x8*)((const ushort_t*)Xv + (size_t)rA * 128 + k0 + lk * 8);
    } else {
      const float* xp = (const float*)Xv + (size_t)rA * 128 + k0 + lk * 8;
      float4 f0 = *(const float4*)xp;
      float4 f1 = *(const float4*)(xp + 4);
      bf16x8 tmp;
      tmp[0] = (short)f2bf(f0.x); tmp[1] = (short)f2bf(f0.y);
      tmp[2] = (short)f2bf(f0.z); tmp[3] = (short)f2bf(f0.w);
      tmp[4] = (short)f2bf(f1.x); tmp[5] = (short)f2bf(f1.y);
      tmp[6] = (short)f2bf(f1.z); tmp[7] = (short)f2bf(f1.w);
      a = tmp;
    }
    int koff = k0 * 2 + lk * 16;
#pragma unroll
    for (int tl = 0; tl < 8; ++tl) {
      int j = tl * 16 + lrow;  // output col = Wt row
      bf16x8 b = *(const bf16x8*)((const char*)wt + j * 256 + (koff ^ ((j & 7) << 4)));
      acc[tl] = __builtin_amdgcn_mfma_f32_16x16x32_bf16(a, b, acc[tl], 0, 0, 0);
    }
  }

  int robase = blockIdx.x * 64 + w * 16 + (lane >> 4) * 4;
#pragma unroll
  for (int j = 0; j < 4; ++j) {
    int row = robase + j;
    if (row < N) {
      float dv = dinv[row];
#pragma unroll
      for (int tl = 0; tl < 8; ++tl) {
        int col = tl * 16 + lrow;
        float o = (acc[tl][j] - cvec[col]) * dv;
        g[(size_t)row * 128 + col] = f2bf(o);
      }
    }
  }
}

// ---- aggregate: 2 dst nodes per wave (32 lanes x 4 cols), pull from CSR ----
template <int LAYER2>
__global__ __launch_bounds__(256) void aggregate_kernel(
    const int* __restrict__ rowptr, const int* __restrict__ adj,
    const ushort_t* __restrict__ g, const float* __restrict__ dinv,
    const float* __restrict__ b, void* __restrict__ out, int N) {
  int t = blockIdx.x * blockDim.x + threadIdx.x;
  int d = t >> 5;
  if (d >= N) return;
  int lc = t & 31;  // cols lc*4 .. lc*4+3
  const ushort_t* gp = g + lc * 4;
  int beg = rowptr[d], end = rowptr[d + 1];

  ushort4 sv = *(const ushort4*)(gp + (size_t)d * 128);  // self loop
  float s0 = bf2f(sv.x), s1 = bf2f(sv.y), s2 = bf2f(sv.z), s3 = bf2f(sv.w);

  int i = beg;
  for (; i + 8 <= end; i += 8) {
    int n0 = adj[i],     n1 = adj[i + 1], n2 = adj[i + 2], n3 = adj[i + 3];
    int n4 = adj[i + 4], n5 = adj[i + 5], n6 = adj[i + 6], n7 = adj[i + 7];
    ushort4 v0 = *(const ushort4*)(gp + (size_t)n0 * 128);
    ushort4 v1 = *(const ushort4*)(gp + (size_t)n1 * 128);
    ushort4 v2 = *(const ushort4*)(gp + (size_t)n2 * 128);
    ushort4 v3 = *(const ushort4*)(gp + (size_t)n3 * 128);
    ushort4 v4 = *(const ushort4*)(gp + (size_t)n4 * 128);
    ushort4 v5 = *(const ushort4*)(gp + (size_t)n5 * 128);
    ushort4 v6 = *(const ushort4*)(gp + (size_t)n6 * 128);
    ushort4 v7 = *(const ushort4*)(gp + (size_t)n7 * 128);
    s0 += ((bf2f(v0.x) + bf2f(v1.x)) + (bf2f(v2.x) + bf2f(v3.x))) +
          ((bf2f(v4.x) + bf2f(v5.x)) + (bf2f(v6.x) + bf2f(v7.x)));
    s1 += ((bf2f(v0.y) + bf2f(v1.y)) + (bf2f(v2.y) + bf2f(v3.y))) +
          ((bf2f(v4.y) + bf2f(v5.y)) + (bf2f(v6.y) + bf2f(v7.y)));
    s2 += ((bf2f(v0.z) + bf2f(v1.z)) + (bf2f(v2.z) + bf2f(v3.z))) +
          ((bf2f(v4.z) + bf2f(v5.z)) + (bf2f(v6.z) + bf2f(v7.z)));
    s3 += ((bf2f(v0.w) + bf2f(v1.w)) + (bf2f(v2.w) + bf2f(v3.w))) +
          ((bf2f(v4.w) + bf2f(v5.w)) + (bf2f(v6.w) + bf2f(v7.w)));
  }
  for (; i < end; ++i) {
    int s = adj[i];
    ushort4 v = *(const ushort4*)(gp + (size_t)s * 128);
    s0 += bf2f(v.x); s1 += bf2f(v.y); s2 += bf2f(v.z); s3 += bf2f(v.w);
  }

  float dv = dinv[d];
  const float4 bb = *(const float4*)&b[lc * 4];
  float o0 = dv * s0 + bb.x, o1 = dv * s1 + bb.y;
  float o2 = dv * s2 + bb.z, o3 = dv * s3 + bb.w;
  if (!LAYER2) {  // relu + bf16 store
    o0 = fmaxf(o0, 0.f); o1 = fmaxf(o1, 0.f);
    o2 = fmaxf(o2, 0.f); o3 = fmaxf(o3, 0.f);
    ushort4 ov;
    ov.x = f2bf(o0); ov.y = f2bf(o1); ov.z = f2bf(o2); ov.w = f2bf(o3);
    *(ushort4*)((ushort_t*)out + (size_t)d * 128 + lc * 4) = ov;
  } else {
    float4 ov; ov.x = o0; ov.y = o1; ov.z = o2; ov.w = o3;
    *(float4*)((float*)out + (size_t)d * 128 + lc * 4) = ov;
  }
}

extern "C" void kernel_launch(void* const* d_in, const int* in_sizes, int n_in,
                              void* d_out, int out_size, void* d_ws, size_t ws_size,
                              hipStream_t stream) {
  const float* features = (const float*)d_in[0];
  const float* W1 = (const float*)d_in[1];
  const float* b1 = (const float*)d_in[2];
  const float* W2 = (const float*)d_in[3];
  const float* b2 = (const float*)d_in[4];
  const void* edges = d_in[5];
  const int N = in_sizes[0] / 128;
  const int E = in_sizes[5] / 2;
  const int NB = (N + SB - 1) / SB;

  // pack bits: src needs ceil(log2(N)), dloc needs ceil(log2(maxslice+1))
  int srcbits = 1; while ((1LL << srcbits) < (long long)N) srcbits++;
  int dmax = N - (int)(((long long)N * 7) >> 3) + 1;
  int dbits = 1; while ((1LL << dbits) < (long long)dmax) dbits++;
  int cap = (srcbits + dbits <= 32) ? ((E / 16 > 2048) ? E / 16 : 2048) : 0;
  const int ovfcap = E;

  float* ws = (float*)d_ws;
  size_t off = 0;
  ushort_t* gbuf = (ushort_t*)(ws + off);  off += (size_t)N * 64;  // bf16 N x 128
  ushort_t* h1 = (ushort_t*)(ws + off);    off += (size_t)N * 64;  // bf16 N x 128
  int* rowptr = (int*)(ws + off);      off += N + 4;
  int* cursor = (int*)(ws + off);      off += N + 4;
  int* adj = (int*)(ws + off);         off += E;
  int* deg = (int*)(ws + off);         off += N + 4;
  float* dinv = ws + off;              off += N + 4;
  int* bsum = (int*)(ws + off);        off += NB + 4;
  unsigned* minenc = (unsigned*)(ws + off); off += 128;
  unsigned* maxenc = (unsigned*)(ws + off); off += 128;
  ushort_t* Wt1 = (ushort_t*)(ws + off);    off += 128 * 64;
  ushort_t* Wt2 = (ushort_t*)(ws + off);    off += 128 * 64;
  float* cvec = ws + off;              off += 128;
  float* czero = ws + off;             off += 128;
  int* flag64 = (int*)(ws + off);      off += 4;
  int* ctrl = (int*)(ws + off);        off += 128;  // queues + bucket cursors
  unsigned* bucket = (unsigned*)(ws + off); off += (size_t)64 * cap;
  int* ovf = (int*)(ws + off);         off += 2 * (size_t)ovfcap;

  float* outf = (float*)d_out;

  // ---- graph prep ----
  detect_kernel<<<1, 1, 0, stream>>>((const int*)edges, E, flag64);
  init_kernel<<<(N + 255) / 256, 256, 0, stream>>>(minenc, maxenc, deg, ctrl, N);
  colminmax_kernel<<<512, 256, 0, stream>>>(features, minenc, maxenc, N);
  bucket_kernel<<<1024, 256, 0, stream>>>(edges, E, flag64, deg, bucket, cap,
                                          ovf, ovfcap, ctrl, N, srcbits);
  prep_kernel<<<1, 128, 0, stream>>>(minenc, maxenc, W1, W2, Wt1, Wt2, cvec, czero);
  scan1_kernel<<<NB, SB, 0, stream>>>(deg, rowptr, bsum, N);
  scan2_kernel<<<1, SB, 0, stream>>>(bsum, NB);
  scan3_kernel<<<NB, SB, 0, stream>>>(rowptr, cursor, bsum, N, E);
  dinv_kernel<<<(N + 255) / 256, 256, 0, stream>>>(deg, dinv, N);
  csrfill_kernel<<<1024, 256, 0, stream>>>(bucket, cap, ovf, ovfcap, cursor, adj,
                                           ctrl, N, srcbits);

  // ---- layer 1 ----
  gemm_mfma_kernel<0><<<(N + 63) / 64, 256, 0, stream>>>(
      features, Wt1, cvec, dinv, gbuf, N);
  aggregate_kernel<0><<<((size_t)N * 32 + 255) / 256, 256, 0, stream>>>(
      rowptr, adj, gbuf, dinv, b1, h1, N);

  // ---- layer 2 ----
  gemm_mfma_kernel<1><<<(N + 63) / 64, 256, 0, stream>>>(
      h1, Wt2, czero, dinv, gbuf, N);
  aggregate_kernel<1><<<((size_t)N * 32 + 255) / 256, 256, 0, stream>>>(
      rowptr, adj, gbuf, dinv, b2, outf, N);
}

// Round 7
// 432.092 us; speedup vs baseline: 7.8099x; 7.8099x over previous
//
#include <hip/hip_runtime.h>

// ---------------------------------------------------------------------------
// MORAL 2-layer GCN on MI355X — round 7.
//   = round-5 structure (best so far, 425us) + the diagnosed fill fix:
//   XCD-local fill (writes confined to L2-resident 1/8 adj slice)  [r5]
//   + NT edge loads so the 25.6MB edge stream bypasses L2          [r4]
//   + src loaded only for in-slice edges (1/8 of lanes).
//   r6's bucket design reverted (64-address returning-atomic contention).
// ---------------------------------------------------------------------------

typedef short bf16x8 __attribute__((ext_vector_type(8)));
typedef float f32x4 __attribute__((ext_vector_type(4)));
typedef unsigned short ushort_t;

__device__ __forceinline__ unsigned encf(float f) {
  unsigned u = __float_as_uint(f);
  return (u & 0x80000000u) ? ~u : (u | 0x80000000u);
}
__device__ __forceinline__ float decf(unsigned e) {
  unsigned u = (e & 0x80000000u) ? (e ^ 0x80000000u) : ~e;
  return __uint_as_float(u);
}
__device__ __forceinline__ ushort_t f2bf(float f) {
  unsigned u = __float_as_uint(f);
  u += 0x7FFF + ((u >> 16) & 1);  // RNE
  return (ushort_t)(u >> 16);
}
__device__ __forceinline__ float bf2f(ushort_t h) {
  return __uint_as_float((unsigned)h << 16);
}

// edges may arrive as int32 or int64 (JAX x64 flag unknown). Detect on device.
__global__ void detect_kernel(const int* __restrict__ edges, int E, int* flag64) {
  if (threadIdx.x == 0 && blockIdx.x == 0) {
    int n = (2 * E < 256) ? 2 * E : 256;
    int all_odd_zero = 1;
    for (int i = 1; i < n; i += 2)
      if (edges[i] != 0) { all_odd_zero = 0; break; }
    *flag64 = all_odd_zero;
  }
}

__global__ void init_kernel(unsigned* minenc, unsigned* maxenc, int* deg,
                            int* workq, int N) {
  int i = blockIdx.x * blockDim.x + threadIdx.x;
  if (i < 128) { minenc[i] = 0xFFFFFFFFu; maxenc[i] = 0u; }
  if (i < 16) workq[i] = 0;
  if (i < N) deg[i] = 0;
}

__global__ void colminmax_kernel(const float* __restrict__ x, unsigned* minenc,
                                 unsigned* maxenc, int N) {
  int g = blockIdx.x * blockDim.x + threadIdx.x;
  int col = g & 127;
  int r0 = g >> 7;
  int nstream = (gridDim.x * blockDim.x) >> 7;
  float mn = 3.4e38f, mx = -3.4e38f;
  for (int r = r0; r < N; r += nstream) {
    float v = x[(size_t)r * 128 + col];
    mn = fminf(mn, v); mx = fmaxf(mx, v);
  }
  atomicMin(&minenc[col], encf(mn));
  atomicMax(&maxenc[col], encf(mx));
}

// Wt1[j][k] = bf16(s[k]*W1[k][j]); cvec[j] = sum_k mn[k]*float(Wt1[j][k])
// Wt2[j][k] = bf16(W2[k][j]); czero = 0
__global__ void prep_kernel(const unsigned* __restrict__ minenc,
                            const unsigned* __restrict__ maxenc,
                            const float* __restrict__ W1, const float* __restrict__ W2,
                            ushort_t* __restrict__ Wt1, ushort_t* __restrict__ Wt2,
                            float* __restrict__ cvec, float* __restrict__ czero) {
  __shared__ float mn_s[128], s_s[128];
  int j = threadIdx.x;
  float mn = decf(minenc[j]);
  float mx = decf(maxenc[j]);
  float denom = (mx > mn) ? (mx - mn) : 1.0f;
  mn_s[j] = mn; s_s[j] = 1.0f / denom;
  __syncthreads();
  float c = 0.f;
  for (int k = 0; k < 128; ++k) {
    float wp = s_s[k] * W1[k * 128 + j];
    ushort_t wb = f2bf(wp);
    Wt1[j * 128 + k] = wb;
    c += mn_s[k] * bf2f(wb);  // fold against the ROUNDED weight so it cancels
    Wt2[j * 128 + k] = f2bf(W2[k * 128 + j]);
  }
  cvec[j] = c;
  czero[j] = 0.f;
}

__global__ void deg_kernel(const void* __restrict__ edges, int E,
                           const int* __restrict__ flag64, int* __restrict__ deg) {
  int e = blockIdx.x * blockDim.x + threadIdx.x;
  if (e >= E) return;
  int d;
  if (*flag64) d = (int)__builtin_nontemporal_load((const long long*)edges + E + e);
  else         d = __builtin_nontemporal_load((const int*)edges + E + e);
  atomicAdd(&deg[d], 1);
}

__global__ void dinv_kernel(const int* __restrict__ deg, float* __restrict__ dinv, int N) {
  int i = blockIdx.x * blockDim.x + threadIdx.x;
  if (i < N) dinv[i] = rsqrtf((float)deg[i] + 1.0f);  // +1 = self loop
}

// ---- prefix scan: deg -> rowptr (exclusive) --------------------------------
#define SB 256

__global__ void scan1_kernel(const int* __restrict__ deg, int* __restrict__ rowptr,
                             int* __restrict__ bsum, int N) {
  __shared__ int tmp[SB];
  int i = blockIdx.x * SB + threadIdx.x;
  int v = (i < N) ? deg[i] : 0;
  tmp[threadIdx.x] = v;
  __syncthreads();
  for (int off = 1; off < SB; off <<= 1) {
    int t = (threadIdx.x >= off) ? tmp[threadIdx.x - off] : 0;
    __syncthreads();
    tmp[threadIdx.x] += t;
    __syncthreads();
  }
  if (i < N) rowptr[i] = tmp[threadIdx.x] - v;
  if (threadIdx.x == 0) bsum[blockIdx.x] = tmp[SB - 1];
}

__global__ void scan2_kernel(int* __restrict__ bsum, int nb) {
  __shared__ int tmp[SB];
  int carry = 0;
  for (int base = 0; base < nb; base += SB) {
    int i = base + threadIdx.x;
    int v = (i < nb) ? bsum[i] : 0;
    tmp[threadIdx.x] = v;
    __syncthreads();
    for (int off = 1; off < SB; off <<= 1) {
      int t = (threadIdx.x >= off) ? tmp[threadIdx.x - off] : 0;
      __syncthreads();
      tmp[threadIdx.x] += t;
      __syncthreads();
    }
    if (i < nb) bsum[i] = carry + tmp[threadIdx.x] - v;
    carry += tmp[SB - 1];
    __syncthreads();
  }
}

__global__ void scan3_kernel(int* __restrict__ rowptr, int* __restrict__ cursor,
                             const int* __restrict__ bsum, int N, int E) {
  int i = blockIdx.x * SB + threadIdx.x;
  if (i < N) {
    int v = rowptr[i] + bsum[blockIdx.x];
    rowptr[i] = v;
    cursor[i] = v;
  }
  if (i == 0) rowptr[N] = E;
}

// ---- XCD-local CSR fill with NT edge stream ---------------------------------
// Each workgroup handles only dsts in its XCD's 1/8 node slice, so its adj
// writes cover an L2-resident ~0.8MB region. NT loads keep the 25.6MB edge
// stream OUT of L2 (served by L3), so partially-filled adj lines are not
// evicted before all 16 entries arrive. src loaded only for in-slice edges.
__global__ __launch_bounds__(256) void fill_kernel(
    const void* __restrict__ edges, int E, const int* __restrict__ flag64,
    int* __restrict__ cursor, int* __restrict__ adj, int* __restrict__ workq,
    int N) {
  int xcd;
  asm volatile("s_getreg_b32 %0, hwreg(HW_REG_XCC_ID)" : "=s"(xcd));
  xcd &= 7;
  const int nlo = (int)(((long long)N * xcd) >> 3);
  const int nhi = (int)(((long long)N * (xcd + 1)) >> 3);
  const int is64 = *flag64;
  const int ITER = 8;
  const int CHUNK = 256 * ITER;
  __shared__ int chunk_s;

  for (;;) {
    __syncthreads();
    if (threadIdx.x == 0) chunk_s = atomicAdd(&workq[xcd], 1);
    __syncthreads();
    long long base = (long long)chunk_s * CHUNK;
    if (base >= E) break;
#pragma unroll
    for (int i = 0; i < ITER; ++i) {
      int e = (int)base + i * 256 + threadIdx.x;
      if (e < E) {
        int d;
        if (is64) d = (int)__builtin_nontemporal_load((const long long*)edges + E + e);
        else      d = __builtin_nontemporal_load((const int*)edges + E + e);
        if (d >= nlo && d < nhi) {
          int s;
          if (is64) s = (int)__builtin_nontemporal_load((const long long*)edges + e);
          else      s = __builtin_nontemporal_load((const int*)edges + e);
          int pos = atomicAdd(&cursor[d], 1);
          adj[pos] = s;
        }
      }
    }
  }
}

// ---- MFMA GEMM: g[bf16] = (X @ Wt^T - cvec) * dinv[row] --------------------
// Wt is [128 out-cols][128 k] bf16. Block = 256 thr = 4 waves; wave w computes
// rows blk*64+16w..+15 x all 128 cols via 8 col-tiles.
template <int XBF16>
__global__ __launch_bounds__(256) void gemm_mfma_kernel(
    const void* __restrict__ Xv, const ushort_t* __restrict__ Wtg,
    const float* __restrict__ cvec, const float* __restrict__ dinv,
    ushort_t* __restrict__ g, int N) {
  __shared__ ushort_t wt[128 * 128];  // XOR-swizzled: byte = j*256 + (k*2 ^ ((j&7)<<4))
  int t = threadIdx.x;
  for (int c = t; c < 2048; c += 256) {  // 2048 x 16B chunks
    int j = c >> 4;
    int ko = (c & 15) << 4;  // byte offset within row
    uint4 v = *(const uint4*)(Wtg + j * 128 + (ko >> 1));
    *(uint4*)((char*)wt + j * 256 + (ko ^ ((j & 7) << 4))) = v;
  }
  __syncthreads();

  int lane = t & 63, w = t >> 6;
  int lrow = lane & 15;      // A-row / B-col within fragment
  int lk = lane >> 4;        // k-group (8 bf16 each)
  int rowA = blockIdx.x * 64 + w * 16 + lrow;
  int rA = (rowA < N) ? rowA : (N - 1);

  f32x4 acc[8];
#pragma unroll
  for (int i = 0; i < 8; ++i) acc[i] = (f32x4){0.f, 0.f, 0.f, 0.f};

#pragma unroll
  for (int ks = 0; ks < 4; ++ks) {
    int k0 = ks * 32;
    bf16x8 a;
    if (XBF16) {
      a = *(const bf16x8*)((const ushort_t*)Xv + (size_t)rA * 128 + k0 + lk * 8);
    } else {
      const float* xp = (const float*)Xv + (size_t)rA * 128 + k0 + lk * 8;
      float4 f0 = *(const float4*)xp;
      float4 f1 = *(const float4*)(xp + 4);
      bf16x8 tmp;
      tmp[0] = (short)f2bf(f0.x); tmp[1] = (short)f2bf(f0.y);
      tmp[2] = (short)f2bf(f0.z); tmp[3] = (short)f2bf(f0.w);
      tmp[4] = (short)f2bf(f1.x); tmp[5] = (short)f2bf(f1.y);
      tmp[6] = (short)f2bf(f1.z); tmp[7] = (short)f2bf(f1.w);
      a = tmp;
    }
    int koff = k0 * 2 + lk * 16;
#pragma unroll
    for (int tl = 0; tl < 8; ++tl) {
      int j = tl * 16 + lrow;  // output col = Wt row
      bf16x8 b = *(const bf16x8*)((const char*)wt + j * 256 + (koff ^ ((j & 7) << 4)));
      acc[tl] = __builtin_amdgcn_mfma_f32_16x16x32_bf16(a, b, acc[tl], 0, 0, 0);
    }
  }

  int robase = blockIdx.x * 64 + w * 16 + (lane >> 4) * 4;
#pragma unroll
  for (int j = 0; j < 4; ++j) {
    int row = robase + j;
    if (row < N) {
      float dv = dinv[row];
#pragma unroll
      for (int tl = 0; tl < 8; ++tl) {
        int col = tl * 16 + lrow;
        float o = (acc[tl][j] - cvec[col]) * dv;
        g[(size_t)row * 128 + col] = f2bf(o);
      }
    }
  }
}

// ---- aggregate: 2 dst nodes per wave (32 lanes x 4 cols), pull from CSR ----
// out[d] = act(dinv[d] * (g[d] + sum_{s in adj[d]} g[s]) + b)
template <int LAYER2>
__global__ __launch_bounds__(256) void aggregate_kernel(
    const int* __restrict__ rowptr, const int* __restrict__ adj,
    const ushort_t* __restrict__ g, const float* __restrict__ dinv,
    const float* __restrict__ b, void* __restrict__ out, int N) {
  int t = blockIdx.x * blockDim.x + threadIdx.x;
  int d = t >> 5;
  if (d >= N) return;
  int lc = t & 31;  // cols lc*4 .. lc*4+3
  const ushort_t* gp = g + lc * 4;
  int beg = rowptr[d], end = rowptr[d + 1];

  ushort4 sv = *(const ushort4*)(gp + (size_t)d * 128);  // self loop
  float s0 = bf2f(sv.x), s1 = bf2f(sv.y), s2 = bf2f(sv.z), s3 = bf2f(sv.w);

  int i = beg;
  for (; i + 8 <= end; i += 8) {
    int n0 = adj[i],     n1 = adj[i + 1], n2 = adj[i + 2], n3 = adj[i + 3];
    int n4 = adj[i + 4], n5 = adj[i + 5], n6 = adj[i + 6], n7 = adj[i + 7];
    ushort4 v0 = *(const ushort4*)(gp + (size_t)n0 * 128);
    ushort4 v1 = *(const ushort4*)(gp + (size_t)n1 * 128);
    ushort4 v2 = *(const ushort4*)(gp + (size_t)n2 * 128);
    ushort4 v3 = *(const ushort4*)(gp + (size_t)n3 * 128);
    ushort4 v4 = *(const ushort4*)(gp + (size_t)n4 * 128);
    ushort4 v5 = *(const ushort4*)(gp + (size_t)n5 * 128);
    ushort4 v6 = *(const ushort4*)(gp + (size_t)n6 * 128);
    ushort4 v7 = *(const ushort4*)(gp + (size_t)n7 * 128);
    s0 += ((bf2f(v0.x) + bf2f(v1.x)) + (bf2f(v2.x) + bf2f(v3.x))) +
          ((bf2f(v4.x) + bf2f(v5.x)) + (bf2f(v6.x) + bf2f(v7.x)));
    s1 += ((bf2f(v0.y) + bf2f(v1.y)) + (bf2f(v2.y) + bf2f(v3.y))) +
          ((bf2f(v4.y) + bf2f(v5.y)) + (bf2f(v6.y) + bf2f(v7.y)));
    s2 += ((bf2f(v0.z) + bf2f(v1.z)) + (bf2f(v2.z) + bf2f(v3.z))) +
          ((bf2f(v4.z) + bf2f(v5.z)) + (bf2f(v6.z) + bf2f(v7.z)));
    s3 += ((bf2f(v0.w) + bf2f(v1.w)) + (bf2f(v2.w) + bf2f(v3.w))) +
          ((bf2f(v4.w) + bf2f(v5.w)) + (bf2f(v6.w) + bf2f(v7.w)));
  }
  for (; i < end; ++i) {
    int s = adj[i];
    ushort4 v = *(const ushort4*)(gp + (size_t)s * 128);
    s0 += bf2f(v.x); s1 += bf2f(v.y); s2 += bf2f(v.z); s3 += bf2f(v.w);
  }

  float dv = dinv[d];
  const float4 bb = *(const float4*)&b[lc * 4];
  float o0 = dv * s0 + bb.x, o1 = dv * s1 + bb.y;
  float o2 = dv * s2 + bb.z, o3 = dv * s3 + bb.w;
  if (!LAYER2) {  // relu + bf16 store
    o0 = fmaxf(o0, 0.f); o1 = fmaxf(o1, 0.f);
    o2 = fmaxf(o2, 0.f); o3 = fmaxf(o3, 0.f);
    ushort4 ov;
    ov.x = f2bf(o0); ov.y = f2bf(o1); ov.z = f2bf(o2); ov.w = f2bf(o3);
    *(ushort4*)((ushort_t*)out + (size_t)d * 128 + lc * 4) = ov;
  } else {
    float4 ov; ov.x = o0; ov.y = o1; ov.z = o2; ov.w = o3;
    *(float4*)((float*)out + (size_t)d * 128 + lc * 4) = ov;
  }
}

extern "C" void kernel_launch(void* const* d_in, const int* in_sizes, int n_in,
                              void* d_out, int out_size, void* d_ws, size_t ws_size,
                              hipStream_t stream) {
  const float* features = (const float*)d_in[0];
  const float* W1 = (const float*)d_in[1];
  const float* b1 = (const float*)d_in[2];
  const float* W2 = (const float*)d_in[3];
  const float* b2 = (const float*)d_in[4];
  const void* edges = d_in[5];
  const int N = in_sizes[0] / 128;
  const int E = in_sizes[5] / 2;
  const int NB = (N + SB - 1) / SB;

  float* ws = (float*)d_ws;
  size_t off = 0;
  ushort_t* gbuf = (ushort_t*)(ws + off);  off += (size_t)N * 64;  // bf16 N x 128
  ushort_t* h1 = (ushort_t*)(ws + off);    off += (size_t)N * 64;  // bf16 N x 128
  int* rowptr = (int*)(ws + off);      off += N + 4;
  int* cursor = (int*)(ws + off);      off += N + 4;
  int* adj = (int*)(ws + off);         off += E;
  int* deg = (int*)(ws + off);         off += N + 4;
  float* dinv = ws + off;              off += N + 4;
  int* bsum = (int*)(ws + off);        off += NB + 4;
  unsigned* minenc = (unsigned*)(ws + off); off += 128;
  unsigned* maxenc = (unsigned*)(ws + off); off += 128;
  ushort_t* Wt1 = (ushort_t*)(ws + off);    off += 128 * 64;
  ushort_t* Wt2 = (ushort_t*)(ws + off);    off += 128 * 64;
  float* cvec = ws + off;              off += 128;
  float* czero = ws + off;             off += 128;
  int* flag64 = (int*)(ws + off);      off += 4;
  int* workq = (int*)(ws + off);       off += 16;

  float* outf = (float*)d_out;

  // ---- graph prep ----
  detect_kernel<<<1, 1, 0, stream>>>((const int*)edges, E, flag64);
  init_kernel<<<(N + 255) / 256, 256, 0, stream>>>(minenc, maxenc, deg, workq, N);
  colminmax_kernel<<<512, 256, 0, stream>>>(features, minenc, maxenc, N);
  deg_kernel<<<(E + 255) / 256, 256, 0, stream>>>(edges, E, flag64, deg);
  prep_kernel<<<1, 128, 0, stream>>>(minenc, maxenc, W1, W2, Wt1, Wt2, cvec, czero);
  scan1_kernel<<<NB, SB, 0, stream>>>(deg, rowptr, bsum, N);
  scan2_kernel<<<1, SB, 0, stream>>>(bsum, NB);
  scan3_kernel<<<NB, SB, 0, stream>>>(rowptr, cursor, bsum, N, E);
  dinv_kernel<<<(N + 255) / 256, 256, 0, stream>>>(deg, dinv, N);
  fill_kernel<<<1024, 256, 0, stream>>>(edges, E, flag64, cursor, adj, workq, N);

  // ---- layer 1 ----
  gemm_mfma_kernel<0><<<(N + 63) / 64, 256, 0, stream>>>(
      features, Wt1, cvec, dinv, gbuf, N);
  aggregate_kernel<0><<<((size_t)N * 32 + 255) / 256, 256, 0, stream>>>(
      rowptr, adj, gbuf, dinv, b1, h1, N);

  // ---- layer 2 ----
  gemm_mfma_kernel<1><<<(N + 63) / 64, 256, 0, stream>>>(
      h1, Wt2, czero, dinv, gbuf, N);
  aggregate_kernel<1><<<((size_t)N * 32 + 255) / 256, 256, 0, stream>>>(
      rowptr, adj, gbuf, dinv, b2, outf, N);
}

// Round 8
// 293.525 us; speedup vs baseline: 11.4968x; 1.4721x over previous
//
#include <hip/hip_runtime.h>

// ---------------------------------------------------------------------------
// MORAL 2-layer GCN on MI355X — round 8.
//   CSR build rewritten as block-level MSB-radix partition + per-bucket build:
//     partition: LDS histogram per 2048-edge chunk -> ONE global atomic per
//       (chunk,bucket) run reservation -> contiguous packed writes into
//       per-(XCD,bucket) staging (dense lines, no cross-XCD sharing).
//     build: one block per bucket; LDS deg count + LDS scan -> rowptr/dinv/
//       gcursor; LDS-cursor placement into contiguous adj window.
//   Replaces deg_kernel + scans + dinv_kernel + fill_kernel (~165us).
//   GEMM (MFMA bf16) and aggregate unchanged from r7.
// ---------------------------------------------------------------------------

typedef short bf16x8 __attribute__((ext_vector_type(8)));
typedef float f32x4 __attribute__((ext_vector_type(4)));
typedef unsigned short ushort_t;

__device__ __forceinline__ unsigned encf(float f) {
  unsigned u = __float_as_uint(f);
  return (u & 0x80000000u) ? ~u : (u | 0x80000000u);
}
__device__ __forceinline__ float decf(unsigned e) {
  unsigned u = (e & 0x80000000u) ? (e ^ 0x80000000u) : ~e;
  return __uint_as_float(u);
}
__device__ __forceinline__ ushort_t f2bf(float f) {
  unsigned u = __float_as_uint(f);
  u += 0x7FFF + ((u >> 16) & 1);  // RNE
  return (ushort_t)(u >> 16);
}
__device__ __forceinline__ float bf2f(ushort_t h) {
  return __uint_as_float((unsigned)h << 16);
}

// edges may arrive as int32 or int64 (JAX x64 flag unknown). Detect on device.
__global__ void detect_kernel(const int* __restrict__ edges, int E, int* flag64) {
  if (threadIdx.x == 0 && blockIdx.x == 0) {
    int n = (2 * E < 256) ? 2 * E : 256;
    int all_odd_zero = 1;
    for (int i = 1; i < n; i += 2)
      if (edges[i] != 0) { all_odd_zero = 0; break; }
    *flag64 = all_odd_zero;
  }
}

__global__ void init_kernel(unsigned* minenc, unsigned* maxenc, int* ovf_deg,
                            int* bcur, int* ctrl, int N) {
  int i = blockIdx.x * blockDim.x + threadIdx.x;
  if (i < 128) { minenc[i] = 0xFFFFFFFFu; maxenc[i] = 0u; }
  if (i < 2048) bcur[i] = 0;
  if (i < 32) ctrl[i] = 0;
  if (i < N) ovf_deg[i] = 0;
}

__global__ void colminmax_kernel(const float* __restrict__ x, unsigned* minenc,
                                 unsigned* maxenc, int N) {
  int g = blockIdx.x * blockDim.x + threadIdx.x;
  int col = g & 127;
  int r0 = g >> 7;
  int nstream = (gridDim.x * blockDim.x) >> 7;
  float mn = 3.4e38f, mx = -3.4e38f;
  for (int r = r0; r < N; r += nstream) {
    float v = x[(size_t)r * 128 + col];
    mn = fminf(mn, v); mx = fmaxf(mx, v);
  }
  atomicMin(&minenc[col], encf(mn));
  atomicMax(&maxenc[col], encf(mx));
}

// Wt1[j][k] = bf16(s[k]*W1[k][j]); cvec[j] = sum_k mn[k]*float(Wt1[j][k])
// Wt2[j][k] = bf16(W2[k][j]); czero = 0
__global__ void prep_kernel(const unsigned* __restrict__ minenc,
                            const unsigned* __restrict__ maxenc,
                            const float* __restrict__ W1, const float* __restrict__ W2,
                            ushort_t* __restrict__ Wt1, ushort_t* __restrict__ Wt2,
                            float* __restrict__ cvec, float* __restrict__ czero) {
  __shared__ float mn_s[128], s_s[128];
  int j = threadIdx.x;
  float mn = decf(minenc[j]);
  float mx = decf(maxenc[j]);
  float denom = (mx > mn) ? (mx - mn) : 1.0f;
  mn_s[j] = mn; s_s[j] = 1.0f / denom;
  __syncthreads();
  float c = 0.f;
  for (int k = 0; k < 128; ++k) {
    float wp = s_s[k] * W1[k * 128 + j];
    ushort_t wb = f2bf(wp);
    Wt1[j * 128 + k] = wb;
    c += mn_s[k] * bf2f(wb);  // fold against the ROUNDED weight so it cancels
    Wt2[j * 128 + k] = f2bf(W2[k * 128 + j]);
  }
  cvec[j] = c;
  czero[j] = 0.f;
}

// ---- Phase 1: MSB-radix partition into per-(XCD,bucket) staging runs -------
#define PITER 8
#define PCHUNK 2048

__global__ __launch_bounds__(256) void partition_kernel(
    const void* __restrict__ edges, int E, const int* __restrict__ flag64,
    unsigned* __restrict__ staging, int capx,
    int* __restrict__ ovf, int ovfcap, int* __restrict__ ovf_deg,
    int* __restrict__ bcur, int* __restrict__ ctrl,
    int srcbits, unsigned M, int width) {
  __shared__ unsigned pk_s[PCHUNK];
  __shared__ unsigned char bk_s[PCHUNK];
  __shared__ int hist[256], rbase[256], lcur[256];
  __shared__ int chunk_s;
  int xcd;
  asm volatile("s_getreg_b32 %0, hwreg(HW_REG_XCC_ID)" : "=s"(xcd));
  xcd &= 7;
  const int elo = (int)(((long long)E * xcd) >> 3);
  const int ehi = (int)(((long long)E * (xcd + 1)) >> 3);
  const int is64 = *flag64;
  const int tid = threadIdx.x;

  for (;;) {
    __syncthreads();
    if (tid == 0) chunk_s = atomicAdd(&ctrl[xcd], 1);
    hist[tid] = 0;
    __syncthreads();
    int base = elo + chunk_s * PCHUNK;
    if (base >= ehi) break;
    int cnt = ehi - base; if (cnt > PCHUNK) cnt = PCHUNK;
#pragma unroll
    for (int i = 0; i < PITER; ++i) {
      int idx = i * 256 + tid;
      if (idx < cnt) {
        int e = base + idx;
        int s, d;
        if (is64) {
          s = (int)__builtin_nontemporal_load((const long long*)edges + e);
          d = (int)__builtin_nontemporal_load((const long long*)edges + E + e);
        } else {
          s = __builtin_nontemporal_load((const int*)edges + e);
          d = __builtin_nontemporal_load((const int*)edges + E + e);
        }
        unsigned b = __umulhi((unsigned)d, M);  // b = d / width (exact)
        int dloc = d - (int)b * width;
        pk_s[idx] = ((unsigned)dloc << srcbits) | (unsigned)s;
        bk_s[idx] = (unsigned char)b;
        atomicAdd(&hist[b], 1);
      }
    }
    __syncthreads();
    {
      int h = hist[tid];
      rbase[tid] = h ? atomicAdd(&bcur[xcd * 256 + tid], h) : 0;
      lcur[tid] = 0;
    }
    __syncthreads();
#pragma unroll
    for (int i = 0; i < PITER; ++i) {
      int idx = i * 256 + tid;
      if (idx < cnt) {
        int b = bk_s[idx];
        unsigned p = pk_s[idx];
        int j = atomicAdd(&lcur[b], 1);
        int pos = rbase[b] + j;
        if (pos < capx) {
          staging[((size_t)(xcd * 256 + b)) * capx + pos] = p;
        } else {  // overflow (statistically never for uniform dst)
          int op = atomicAdd(&ctrl[8], 1);
          if (op < ovfcap) {
            int s = (int)(p & ((1u << srcbits) - 1u));
            int d = b * width + (int)(p >> srcbits);
            ovf[2 * op] = s; ovf[2 * op + 1] = d;
            atomicAdd(&ovf_deg[d], 1);
          }
        }
      }
    }
  }
}

// ---- exclusive scan of true bucket totals -> bucket_base -------------------
__global__ void bucketscan_kernel(const int* __restrict__ bcur,
                                  int* __restrict__ bucket_base) {
  __shared__ int tot[256];
  int b = threadIdx.x;
  int t = 0;
  for (int x = 0; x < 8; ++x) t += bcur[x * 256 + b];  // includes overflowed
  tot[b] = t;
  __syncthreads();
  for (int off = 1; off < 256; off <<= 1) {
    int v = (b >= off) ? tot[b - off] : 0;
    __syncthreads();
    tot[b] += v;
    __syncthreads();
  }
  bucket_base[b] = tot[b] - t;
  if (b == 255) bucket_base[256] = tot[255];
}

// ---- Phase 2: per-bucket build (deg, rowptr, dinv, gcursor, adj) -----------
#define WMAX 512

__global__ __launch_bounds__(256) void build_kernel(
    const unsigned* __restrict__ staging, int capx,
    const int* __restrict__ bcur, const int* __restrict__ bucket_base,
    const int* __restrict__ ovf_deg,
    int* __restrict__ rowptr, int* __restrict__ gcursor,
    float* __restrict__ dinv, int* __restrict__ adj,
    int N, int E, int srcbits, int width) {
  __shared__ int cntS[WMAX], scn[WMAX], excl[WMAX], lcur[WMAX];
  int b = blockIdx.x;
  int tid = threadIdx.x;
  int nlo = b * width;
  int wcnt = N - nlo; if (wcnt > width) wcnt = width; if (wcnt < 0) wcnt = 0;

  for (int i = tid; i < WMAX; i += 256) cntS[i] = 0;
  __syncthreads();

  // count staged items per local dst
  for (int x = 0; x < 8; ++x) {
    int len = bcur[x * 256 + b]; if (len > capx) len = capx;
    const unsigned* sp = staging + ((size_t)(x * 256 + b)) * capx;
    for (int i = tid; i < len; i += 256)
      atomicAdd(&cntS[sp[i] >> srcbits], 1);
  }
  __syncthreads();

  // true counts (staged + overflow)
  for (int i = tid; i < WMAX; i += 256) {
    int t = cntS[i] + ((i < wcnt) ? ovf_deg[nlo + i] : 0);
    scn[i] = t;
    excl[i] = t;  // stash original
  }
  __syncthreads();

  // inclusive Hillis-Steele scan over 512 slots (2 elems/thread)
  for (int off = 1; off < WMAX; off <<= 1) {
    int i0 = tid, i1 = tid + 256;
    int v0 = (i0 >= off) ? scn[i0 - off] : 0;
    int v1 = (i1 >= off) ? scn[i1 - off] : 0;
    __syncthreads();
    scn[i0] += v0; scn[i1] += v1;
    __syncthreads();
  }

  int base = bucket_base[b];
  for (int i = tid; i < WMAX; i += 256) {
    int orig = excl[i];
    int ex = scn[i] - orig;
    excl[i] = ex;
    lcur[i] = ex;
    if (i < wcnt) {
      rowptr[nlo + i] = base + ex;
      gcursor[nlo + i] = base + ex + cntS[i];       // overflow goes after staged
      dinv[nlo + i] = rsqrtf((float)orig + 1.0f);   // +1 = self loop
    }
  }
  if (b == gridDim.x - 1 && tid == 0) rowptr[N] = E;
  __syncthreads();

  // place staged items into contiguous adj window via LDS cursors
  for (int x = 0; x < 8; ++x) {
    int len = bcur[x * 256 + b]; if (len > capx) len = capx;
    const unsigned* sp = staging + ((size_t)(x * 256 + b)) * capx;
    for (int i = tid; i < len; i += 256) {
      unsigned p = sp[i];
      int dloc = (int)(p >> srcbits);
      int src = (int)(p & ((1u << srcbits) - 1u));
      int pos = atomicAdd(&lcur[dloc], 1);
      adj[base + pos] = src;
    }
  }
}

// ---- overflow tail (normally empty) ----------------------------------------
__global__ void tail_kernel(const int* __restrict__ ovf, const int* __restrict__ ctrl,
                            int ovfcap, int* __restrict__ gcursor,
                            int* __restrict__ adj) {
  int n = ctrl[8]; if (n > ovfcap) n = ovfcap;
  int stride = gridDim.x * blockDim.x;
  for (int i = blockIdx.x * blockDim.x + threadIdx.x; i < n; i += stride) {
    int s = ovf[2 * i], d = ovf[2 * i + 1];
    int pos = atomicAdd(&gcursor[d], 1);
    adj[pos] = s;
  }
}

// ---- MFMA GEMM: g[bf16] = (X @ Wt^T - cvec) * dinv[row] --------------------
template <int XBF16>
__global__ __launch_bounds__(256) void gemm_mfma_kernel(
    const void* __restrict__ Xv, const ushort_t* __restrict__ Wtg,
    const float* __restrict__ cvec, const float* __restrict__ dinv,
    ushort_t* __restrict__ g, int N) {
  __shared__ ushort_t wt[128 * 128];  // XOR-swizzled: byte = j*256 + (k*2 ^ ((j&7)<<4))
  int t = threadIdx.x;
  for (int c = t; c < 2048; c += 256) {
    int j = c >> 4;
    int ko = (c & 15) << 4;
    uint4 v = *(const uint4*)(Wtg + j * 128 + (ko >> 1));
    *(uint4*)((char*)wt + j * 256 + (ko ^ ((j & 7) << 4))) = v;
  }
  __syncthreads();

  int lane = t & 63, w = t >> 6;
  int lrow = lane & 15;
  int lk = lane >> 4;
  int rowA = blockIdx.x * 64 + w * 16 + lrow;
  int rA = (rowA < N) ? rowA : (N - 1);

  f32x4 acc[8];
#pragma unroll
  for (int i = 0; i < 8; ++i) acc[i] = (f32x4){0.f, 0.f, 0.f, 0.f};

#pragma unroll
  for (int ks = 0; ks < 4; ++ks) {
    int k0 = ks * 32;
    bf16x8 a;
    if (XBF16) {
      a = *(const bf16x8*)((const ushort_t*)Xv + (size_t)rA * 128 + k0 + lk * 8);
    } else {
      const float* xp = (const float*)Xv + (size_t)rA * 128 + k0 + lk * 8;
      float4 f0 = *(const float4*)xp;
      float4 f1 = *(const float4*)(xp + 4);
      bf16x8 tmp;
      tmp[0] = (short)f2bf(f0.x); tmp[1] = (short)f2bf(f0.y);
      tmp[2] = (short)f2bf(f0.z); tmp[3] = (short)f2bf(f0.w);
      tmp[4] = (short)f2bf(f1.x); tmp[5] = (short)f2bf(f1.y);
      tmp[6] = (short)f2bf(f1.z); tmp[7] = (short)f2bf(f1.w);
      a = tmp;
    }
    int koff = k0 * 2 + lk * 16;
#pragma unroll
    for (int tl = 0; tl < 8; ++tl) {
      int j = tl * 16 + lrow;
      bf16x8 bfr = *(const bf16x8*)((const char*)wt + j * 256 + (koff ^ ((j & 7) << 4)));
      acc[tl] = __builtin_amdgcn_mfma_f32_16x16x32_bf16(a, bfr, acc[tl], 0, 0, 0);
    }
  }

  int robase = blockIdx.x * 64 + w * 16 + (lane >> 4) * 4;
#pragma unroll
  for (int j = 0; j < 4; ++j) {
    int row = robase + j;
    if (row < N) {
      float dv = dinv[row];
#pragma unroll
      for (int tl = 0; tl < 8; ++tl) {
        int col = tl * 16 + lrow;
        float o = (acc[tl][j] - cvec[col]) * dv;
        g[(size_t)row * 128 + col] = f2bf(o);
      }
    }
  }
}

// ---- aggregate: 2 dst nodes per wave (32 lanes x 4 cols), pull from CSR ----
template <int LAYER2>
__global__ __launch_bounds__(256) void aggregate_kernel(
    const int* __restrict__ rowptr, const int* __restrict__ adj,
    const ushort_t* __restrict__ g, const float* __restrict__ dinv,
    const float* __restrict__ b, void* __restrict__ out, int N) {
  int t = blockIdx.x * blockDim.x + threadIdx.x;
  int d = t >> 5;
  if (d >= N) return;
  int lc = t & 31;
  const ushort_t* gp = g + lc * 4;
  int beg = rowptr[d], end = rowptr[d + 1];

  ushort4 sv = *(const ushort4*)(gp + (size_t)d * 128);  // self loop
  float s0 = bf2f(sv.x), s1 = bf2f(sv.y), s2 = bf2f(sv.z), s3 = bf2f(sv.w);

  int i = beg;
  for (; i + 8 <= end; i += 8) {
    int n0 = adj[i],     n1 = adj[i + 1], n2 = adj[i + 2], n3 = adj[i + 3];
    int n4 = adj[i + 4], n5 = adj[i + 5], n6 = adj[i + 6], n7 = adj[i + 7];
    ushort4 v0 = *(const ushort4*)(gp + (size_t)n0 * 128);
    ushort4 v1 = *(const ushort4*)(gp + (size_t)n1 * 128);
    ushort4 v2 = *(const ushort4*)(gp + (size_t)n2 * 128);
    ushort4 v3 = *(const ushort4*)(gp + (size_t)n3 * 128);
    ushort4 v4 = *(const ushort4*)(gp + (size_t)n4 * 128);
    ushort4 v5 = *(const ushort4*)(gp + (size_t)n5 * 128);
    ushort4 v6 = *(const ushort4*)(gp + (size_t)n6 * 128);
    ushort4 v7 = *(const ushort4*)(gp + (size_t)n7 * 128);
    s0 += ((bf2f(v0.x) + bf2f(v1.x)) + (bf2f(v2.x) + bf2f(v3.x))) +
          ((bf2f(v4.x) + bf2f(v5.x)) + (bf2f(v6.x) + bf2f(v7.x)));
    s1 += ((bf2f(v0.y) + bf2f(v1.y)) + (bf2f(v2.y) + bf2f(v3.y))) +
          ((bf2f(v4.y) + bf2f(v5.y)) + (bf2f(v6.y) + bf2f(v7.y)));
    s2 += ((bf2f(v0.z) + bf2f(v1.z)) + (bf2f(v2.z) + bf2f(v3.z))) +
          ((bf2f(v4.z) + bf2f(v5.z)) + (bf2f(v6.z) + bf2f(v7.z)));
    s3 += ((bf2f(v0.w) + bf2f(v1.w)) + (bf2f(v2.w) + bf2f(v3.w))) +
          ((bf2f(v4.w) + bf2f(v5.w)) + (bf2f(v6.w) + bf2f(v7.w)));
  }
  for (; i < end; ++i) {
    int s = adj[i];
    ushort4 v = *(const ushort4*)(gp + (size_t)s * 128);
    s0 += bf2f(v.x); s1 += bf2f(v.y); s2 += bf2f(v.z); s3 += bf2f(v.w);
  }

  float dv = dinv[d];
  const float4 bb = *(const float4*)&b[lc * 4];
  float o0 = dv * s0 + bb.x, o1 = dv * s1 + bb.y;
  float o2 = dv * s2 + bb.z, o3 = dv * s3 + bb.w;
  if (!LAYER2) {
    o0 = fmaxf(o0, 0.f); o1 = fmaxf(o1, 0.f);
    o2 = fmaxf(o2, 0.f); o3 = fmaxf(o3, 0.f);
    ushort4 ov;
    ov.x = f2bf(o0); ov.y = f2bf(o1); ov.z = f2bf(o2); ov.w = f2bf(o3);
    *(ushort4*)((ushort_t*)out + (size_t)d * 128 + lc * 4) = ov;
  } else {
    float4 ov; ov.x = o0; ov.y = o1; ov.z = o2; ov.w = o3;
    *(float4*)((float*)out + (size_t)d * 128 + lc * 4) = ov;
  }
}

extern "C" void kernel_launch(void* const* d_in, const int* in_sizes, int n_in,
                              void* d_out, int out_size, void* d_ws, size_t ws_size,
                              hipStream_t stream) {
  const float* features = (const float*)d_in[0];
  const float* W1 = (const float*)d_in[1];
  const float* b1 = (const float*)d_in[2];
  const float* W2 = (const float*)d_in[3];
  const float* b2 = (const float*)d_in[4];
  const void* edges = d_in[5];
  const int N = in_sizes[0] / 128;
  const int E = in_sizes[5] / 2;

  // radix parameters
  int srcbits = 1; while ((1LL << srcbits) < (long long)N) srcbits++;
  const int width = (N + 255) / 256;                       // nodes per bucket
  const unsigned M = (unsigned)(0x100000000ULL / (unsigned)width + 1);  // d/width
  const int capx = (E / 2048) * 3 + 256;                   // per-(XCD,bucket) cap
  const int ovfcap = E / 4;

  float* ws = (float*)d_ws;
  size_t off = 0;
  ushort_t* gbuf = (ushort_t*)(ws + off);  off += (size_t)N * 64;  // bf16 N x 128
  ushort_t* h1 = (ushort_t*)(ws + off);    off += (size_t)N * 64;  // bf16 N x 128
  int* rowptr = (int*)(ws + off);      off += N + 4;
  int* gcursor = (int*)(ws + off);     off += N + 4;
  int* adj = (int*)(ws + off);         off += E;
  int* ovf_deg = (int*)(ws + off);     off += N + 4;
  float* dinv = ws + off;              off += N + 4;
  unsigned* minenc = (unsigned*)(ws + off); off += 128;
  unsigned* maxenc = (unsigned*)(ws + off); off += 128;
  ushort_t* Wt1 = (ushort_t*)(ws + off);    off += 128 * 64;
  ushort_t* Wt2 = (ushort_t*)(ws + off);    off += 128 * 64;
  float* cvec = ws + off;              off += 128;
  float* czero = ws + off;             off += 128;
  int* flag64 = (int*)(ws + off);      off += 4;
  int* ctrl = (int*)(ws + off);        off += 32;
  int* bcur = (int*)(ws + off);        off += 2048;
  int* bucket_base = (int*)(ws + off); off += 260;
  unsigned* staging = (unsigned*)(ws + off); off += (size_t)2048 * capx;
  int* ovf = (int*)(ws + off);         off += 2 * (size_t)ovfcap;

  float* outf = (float*)d_out;

  // ---- graph prep ----
  detect_kernel<<<1, 1, 0, stream>>>((const int*)edges, E, flag64);
  init_kernel<<<(N + 255) / 256, 256, 0, stream>>>(minenc, maxenc, ovf_deg, bcur, ctrl, N);
  colminmax_kernel<<<512, 256, 0, stream>>>(features, minenc, maxenc, N);
  partition_kernel<<<1024, 256, 0, stream>>>(edges, E, flag64, staging, capx,
                                             ovf, ovfcap, ovf_deg, bcur, ctrl,
                                             srcbits, M, width);
  bucketscan_kernel<<<1, 256, 0, stream>>>(bcur, bucket_base);
  build_kernel<<<256, 256, 0, stream>>>(staging, capx, bcur, bucket_base, ovf_deg,
                                        rowptr, gcursor, dinv, adj, N, E, srcbits, width);
  tail_kernel<<<64, 256, 0, stream>>>(ovf, ctrl, ovfcap, gcursor, adj);
  prep_kernel<<<1, 128, 0, stream>>>(minenc, maxenc, W1, W2, Wt1, Wt2, cvec, czero);

  // ---- layer 1 ----
  gemm_mfma_kernel<0><<<(N + 63) / 64, 256, 0, stream>>>(
      features, Wt1, cvec, dinv, gbuf, N);
  aggregate_kernel<0><<<((size_t)N * 32 + 255) / 256, 256, 0, stream>>>(
      rowptr, adj, gbuf, dinv, b1, h1, N);

  // ---- layer 2 ----
  gemm_mfma_kernel<1><<<(N + 63) / 64, 256, 0, stream>>>(
      h1, Wt2, czero, dinv, gbuf, N);
  aggregate_kernel<1><<<((size_t)N * 32 + 255) / 256, 256, 0, stream>>>(
      rowptr, adj, gbuf, dinv, b2, outf, N);
}